// Round 4
// baseline (158.663 us; speedup 1.0000x reference)
//
#include <hip/hip_runtime.h>
#include <math.h>

#define BB 32
#define CCH 224
#define TTT 2048
#define BT (BB*TTT)        // 65536
#define TPB 64             // t per tile in kf
#define NT  (TTT/TPB)      // 32 tiles
#define CG  14             // chains (channels) per kf block
#define NCG (CCH/CG)       // 16  -> 512 blocks = 2 blocks/CU
#define ROWS (CG+12)       // 26 halo rows
#define XROW 68            // floats per xs row (64 + 4 pad, 16B-aligned)
#define IROW 15            // f64 per I row (14 + 1 pad)

// ---------------------------------------------------------------------------
// kw: per (b,t): f64 dot over C -> w -> 7 symmetric Gaussian taps (f64, SoA)
// grid (32 t-tiles, 32 b) x 256: thread = (t in 0..63) x (m in 0..3).
// Identical arithmetic to round 3 (4 partials of 56, (p0+p1)+(p2+p3)).
// ---------------------------------------------------------------------------
__global__ __launch_bounds__(256) void kw(
    const float* __restrict__ x, const float* __restrict__ lw,
    double* __restrict__ kernG)
{
    __shared__ double sd[4][64];
    const int b  = blockIdx.y;
    const int t0 = blockIdx.x * 64;
    const int tt = threadIdx.x & 63;
    const int m  = threadIdx.x >> 6;

    const float* xb = x + (((size_t)(b * CCH + 56 * m)) << 11) + t0 + tt;
    double acc = 0.0;
    #pragma unroll 8
    for (int i = 0; i < 56; ++i)
        acc += (double)xb[(size_t)i << 11] * (double)lw[56 * m + i];
    sd[m][tt] = acc;
    __syncthreads();

    if (threadIdx.x < 64) {
        const int t = threadIdx.x;
        double s2 = (sd[0][t] + sd[1][t]) + (sd[2][t] + sd[3][t]);

        double w = 5.2 + s2 * 9.6;
        w = fmin(fmax(w, 0.4), 10.0);
        double iw2 = 1.0 / (w * w);

        // norm over linspace(-60,60,130): symmetric -> 2x half-sum,
        // terms G^{(2u+1)^2} via power recurrence (2 exps total)
        const double s = 120.0 / 129.0;
        double G  = exp(-0.125 * s * s * iw2);
        double G2 = G * G, G4 = G2 * G2, G8 = G4 * G4;
        double term = G, cmul = G8, norm = G;
        for (int u = 1; u <= 64; ++u) { term *= cmul; cmul *= G8; norm += term; }
        norm *= 2.0;

        double P = exp(-0.5 * iw2), P2 = P * P;
        double a = 1.0, bm = P, inv = 1.0 / norm;
        double* kr = kernG + (size_t)b * TTT + t0 + t;   // SoA: [d][b*T+t]
        kr[0] = inv;
        #pragma unroll
        for (int d = 1; d <= 6; ++d) {
            a *= bm; bm *= P2;
            kr[(size_t)d * BT] = a * inv;
        }
    }
}

// ---------------------------------------------------------------------------
// kf: fused conv + LIF scan + spike output. grid (16, 32) x 192 threads.
// wave0 = scan (14 chains); waves 1-2 = stage/conv/out-write.
// phase k: conv(k)->Is[k&1]; stage(k+1)->xs/kd[(k+1)&1]; scan(k-1) reads
// Is[(k-1)&1] -> bitsb[(k-1)&1]; out-write(k-2) reads bitsb[k&1].
// ---------------------------------------------------------------------------
__global__ __launch_bounds__(192) void kf(
    const float* __restrict__ x, const double* __restrict__ kernG,
    float* __restrict__ out)
{
    __shared__ __align__(16) float xs[2][ROWS][XROW];      // 14144 B
    __shared__ double kd[2][TPB][7];                       //  7168 B
    __shared__ double Is[2][TPB][IROW];                    // 15360 B
    __shared__ unsigned long long bitsb[2][CG];            //   224 B

    const int b   = blockIdx.y;
    const int cgi = blockIdx.x;
    const int c0  = cgi * CG;
    const int tid = threadIdx.x;
    const int ctid = tid - 64;

    const float*  xbase = x + (((size_t)(b * CCH)) << 11);
    const double* kbase = kernG + (size_t)b * TTT;         // SoA: kbase[d*BT + t]
    float* obase = out + (((size_t)(b * CCH + c0)) << 11);

    double mem = 0.0;   // scan state (wave0 lanes)
    bool   r   = false;

    // ---- prologue: stage tile 0 ----
    if (tid >= 64) {
        #pragma unroll
        for (int i2 = 0; i2 < 4; ++i2) {
            int e = ctid + i2 * 128;
            if (e < ROWS * 16) {
                int rr = e >> 4, q = e & 15;
                int cr = c0 - 6 + rr;
                float4 v = make_float4(0.f, 0.f, 0.f, 0.f);
                if (cr >= 0 && cr < CCH)
                    v = *(const float4*)(xbase + ((size_t)cr << 11) + 4 * q);
                *(float4*)&xs[0][rr][4 * q] = v;
            }
        }
        if (ctid < TPB) {
            #pragma unroll
            for (int d = 0; d < 7; ++d)
                kd[0][ctid][d] = kbase[(size_t)d * BT + ctid];
        }
    }
    __syncthreads();

    for (int k = 0; k <= NT + 1; ++k) {
        if (tid >= 64) {
            const int buf = k & 1, nbuf = (k + 1) & 1;
            // 1) issue global loads for tile k+1 (latency hidden under conv)
            float4 rv[4]; double kv[7];
            const bool st = (k + 1 <= NT - 1);
            if (st) {
                const int gt0 = (k + 1) * TPB;
                #pragma unroll
                for (int i2 = 0; i2 < 4; ++i2) {
                    int e = ctid + i2 * 128;
                    rv[i2] = make_float4(0.f, 0.f, 0.f, 0.f);
                    if (e < ROWS * 16) {
                        int rr = e >> 4, q = e & 15;
                        int cr = c0 - 6 + rr;
                        if (cr >= 0 && cr < CCH)
                            rv[i2] = *(const float4*)(xbase + ((size_t)cr << 11) + gt0 + 4 * q);
                    }
                }
                if (ctid < TPB) {
                    #pragma unroll
                    for (int d = 0; d < 7; ++d)
                        kv[d] = kbase[(size_t)d * BT + gt0 + ctid];
                }
            }
            // 2) conv(k): thread = (t, half) -> 7 channels, sliding 13-row ring
            if (k <= NT - 1) {
                const int t  = ctid & 63;
                const int ch = ctid >> 6;       // 0/1
                const int cb = 7 * ch;
                double kk7[7];
                #pragma unroll
                for (int i2 = 0; i2 < 7; ++i2) kk7[i2] = kd[buf][t][i2];
                float xv[13];
                #pragma unroll
                for (int i2 = 0; i2 < 13; ++i2) xv[i2] = xs[buf][cb + i2][t];
                #pragma unroll
                for (int c = 0; c < 7; ++c) {
                    double acc = 0.0;
                    #pragma unroll
                    for (int kk2 = 0; kk2 < 13; ++kk2) {
                        int d = kk2 < 6 ? 6 - kk2 : kk2 - 6;
                        acc = fma((double)xv[(c + kk2) % 13], kk7[d], acc);
                    }
                    double xvv = (double)xv[(c + 6) % 13];
                    double dd  = xvv - acc;
                    Is[buf][t][cb + c] = xvv - (dd > 0.0 ? dd : 0.0);
                    if (c < 6) xv[c % 13] = xs[buf][cb + c + 13][t];
                }
            }
            // 3) out-write(k-2): coalesced float4 spike stores
            if (k >= 2) {
                const int j = k - 2, jb = j & 1;
                const int t0o = j * TPB;
                #pragma unroll
                for (int i2 = 0; i2 < 2; ++i2) {
                    int e = ctid + i2 * 128;
                    if (e < CG * 16) {
                        int c = e >> 4, q = e & 15;
                        unsigned long long bits = bitsb[jb][c] >> (4 * q);
                        float4 v;
                        v.x = (bits & 1ull) ? 1.0f : 0.0f;
                        v.y = (bits & 2ull) ? 1.0f : 0.0f;
                        v.z = (bits & 4ull) ? 1.0f : 0.0f;
                        v.w = (bits & 8ull) ? 1.0f : 0.0f;
                        *(float4*)(obase + ((size_t)c << 11) + t0o + 4 * q) = v;
                    }
                }
            }
            // 4) drain staged regs -> LDS (next buffers)
            if (st) {
                #pragma unroll
                for (int i2 = 0; i2 < 4; ++i2) {
                    int e = ctid + i2 * 128;
                    if (e < ROWS * 16) {
                        int rr = e >> 4, q = e & 15;
                        *(float4*)&xs[nbuf][rr][4 * q] = rv[i2];
                    }
                }
                if (ctid < TPB) {
                    #pragma unroll
                    for (int d = 0; d < 7; ++d) kd[nbuf][ctid][d] = kv[d];
                }
            }
        } else {
            // scan(k-1): 8-deep double-buffered prefetch, short dep chain
            if (k >= 1 && k <= NT) {
                const int p = (k - 1) & 1;
                const int c = tid;
                if (c < CG) {
                    unsigned long long bits = 0ull;
                    double va[8], vb[8];
                    #pragma unroll
                    for (int j2 = 0; j2 < 8; ++j2) va[j2] = Is[p][j2][c];
                    #pragma unroll
                    for (int g = 0; g < 64; g += 16) {
                        #pragma unroll
                        for (int j2 = 0; j2 < 8; ++j2) vb[j2] = Is[p][g + 8 + j2][c];
                        #pragma unroll
                        for (int j2 = 0; j2 < 8; ++j2) {
                            double a2 = va[j2];
                            double cm = a2 - 1.0;
                            double m1 = fma(0.95, mem, a2);
                            double m2 = fma(0.95, mem, cm);
                            mem = r ? m2 : m1;
                            r = mem > 1.0;
                            bits |= (unsigned long long)(r ? 1 : 0) << (g + j2);
                        }
                        if (g + 16 < 64) {
                            #pragma unroll
                            for (int j2 = 0; j2 < 8; ++j2) va[j2] = Is[p][g + 16 + j2][c];
                        }
                        #pragma unroll
                        for (int j2 = 0; j2 < 8; ++j2) {
                            double a2 = vb[j2];
                            double cm = a2 - 1.0;
                            double m1 = fma(0.95, mem, a2);
                            double m2 = fma(0.95, mem, cm);
                            mem = r ? m2 : m1;
                            r = mem > 1.0;
                            bits |= (unsigned long long)(r ? 1 : 0) << (g + 8 + j2);
                        }
                    }
                    bitsb[p][c] = bits;
                }
            }
        }
        __syncthreads();
    }
}

// ---------------------------------------------------------------------------
extern "C" void kernel_launch(void* const* d_in, const int* in_sizes, int n_in,
                              void* d_out, int out_size, void* d_ws, size_t ws_size,
                              hipStream_t stream)
{
    const float* x  = (const float*)d_in[0];   // (32,1,224,2048) f32
    const float* lw = (const float*)d_in[1];   // (1,224) f32
    float* out = (float*)d_out;                // (32,1,224,2048) f32

    double* kernG = (double*)d_ws;             // SoA 7 * 65536 * 8 = 3,670,016 B

    kw<<<dim3(TTT / 64, BB), 256, 0, stream>>>(x, lw, kernG);
    kf<<<dim3(NCG, BB), 192, 0, stream>>>(x, kernG, out);
}